// Round 13
// baseline (5716.555 us; speedup 1.0000x reference)
//
#include <hip/hip_runtime.h>

#define TSTEPS  2048
#define DIN     64
#define UNITS   128
#define UNFOLDS 6
#define NT      512
#define NB      2

// R7-verified skeleton + NB=2 batch ILP (weights shared across batches).
// Thread (g = tid>>4, p = tid&15) owns units {4g..4g+3} x K-chunk [8p,8p+8)
// for BOTH batches 2*bx and 2*bx+1. Per sub-step per batch: 1x ds_read_b128
// (h packed f16), 16 dot2, 5-stage reduce-scatter (lane ends owning unit
// 4g+sel), nonlin once, p<4 publish b16. The two batches' chains interleave
// in-wave, filling the LDS-latency/exp-chain stalls that made R5-R11
// invariant at ~750-820 cyc/sub-step. One raw s_barrier per sub-step.
// f16 ONLY on W and h (RNE); x-projection exact fp32.

typedef _Float16 h16x2 __attribute__((ext_vector_type(2)));

template <int CTRL>
__device__ __forceinline__ float dpp_f(float v) {
    return __int_as_float(
        __builtin_amdgcn_mov_dpp(__float_as_int(v), CTRL, 0xF, 0xF, true));
}

__device__ __forceinline__ float dot2(h16x2 a, h16x2 b, float c) {
#if __has_builtin(__builtin_amdgcn_fdot2)
    return __builtin_amdgcn_fdot2(a, b, c, false);
#else
    return fmaf((float)a.x, (float)b.x, fmaf((float)a.y, (float)b.y, c));
#endif
}

__global__ __launch_bounds__(NT) void ltc_kernel(
    const float* __restrict__ x,      // [B,T,DIN]
    const float* __restrict__ kern,   // [DIN,UNITS]
    const float* __restrict__ rk,     // [UNITS,UNITS]
    const float* __restrict__ bias,   // [UNITS]
    const float* __restrict__ tau,    // [UNITS]
    const float* __restrict__ Avec,   // [UNITS]
    const float* __restrict__ okern,  // [UNITS,1]
    const float* __restrict__ obias,  // [1]
    float* __restrict__ out)          // [B,T,1]
{
    const int tid  = threadIdx.x;
    const int p    = tid & 15;      // K-chunk id
    const int g    = tid >> 4;      // unit group: units 4g..4g+3
    const int wid  = tid >> 6;
    const int lane = tid & 63;

    __shared__ __align__(16) _Float16 hbuf[2][NB][UNITS];
    __shared__ float part[NB][8];

    // resident recurrent weights as f16 K-pairs (SHARED across batches):
    // w2_[m][j] = ( rk[8p+2m][4g+j], rk[8p+2m+1][4g+j] )
    h16x2 w2_[4][4];
    #pragma unroll
    for (int m = 0; m < 4; ++m) {
        const float* r0 = rk + (size_t)(8 * p + 2 * m) * UNITS + 4 * g;
        const float* r1 = r0 + UNITS;
        #pragma unroll
        for (int j = 0; j < 4; ++j) {
            h16x2 v; v.x = (_Float16)r0[j]; v.y = (_Float16)r1[j];
            w2_[m][j] = v;
        }
    }
    // input kernel fp32 (shared): kk_[m][j] = kern[4p+m][4g+j]
    float kk_[4][4];
    #pragma unroll
    for (int m = 0; m < 4; ++m) {
        float4 v = ((const float4*)(kern + (size_t)(4 * p + m) * UNITS))[g];
        kk_[m][0] = v.x; kk_[m][1] = v.y; kk_[m][2] = v.z; kk_[m][3] = v.w;
    }

    const float dt  = 1.0f / 6.0f;
    const int   sel = ((p & 1) << 1) | ((p >> 1) & 1);  // scatter endpoint
    const int   u_own = 4 * g + sel;
    const float dtA_o  = dt * Avec[u_own];
    const float cden_o = 1.0f + dt / tau[u_own];
    const float cdp_o  = cden_o + dt;
    const float ok_o   = okern[u_own];
    float4 bv = ((const float4*)bias)[g];
    float bias4[4] = {bv.x, bv.y, bv.z, bv.w};
    const float ob = obias[0];

    float h_own[NB] = {0.0f, 0.0f};
    if (tid < UNITS) {
        hbuf[0][0][tid] = (_Float16)0.f; hbuf[0][1][tid] = (_Float16)0.f;
        hbuf[1][0][tid] = (_Float16)0.f; hbuf[1][1][tid] = (_Float16)0.f;
    }

    const float* xb[NB];
    xb[0] = x + (size_t)(2 * blockIdx.x) * TSTEPS * DIN;
    xb[1] = xb[0] + (size_t)TSTEPS * DIN;
    float4 xr[NB];
    #pragma unroll
    for (int bt = 0; bt < NB; ++bt) xr[bt] = *(const float4*)(xb[bt] + 4 * p);
    __syncthreads();

    for (int t = 0; t < TSTEPS; ++t) {
        // x-projection partials (fp32 exact), valid all 6 sub-steps
        float xp[NB][4];
        #pragma unroll
        for (int bt = 0; bt < NB; ++bt) {
            #pragma unroll
            for (int i = 0; i < 4; ++i) xp[bt][i] = (p == 0) ? bias4[i] : 0.0f;
            float xrf[4] = {xr[bt].x, xr[bt].y, xr[bt].z, xr[bt].w};
            #pragma unroll
            for (int m = 0; m < 4; ++m)
                #pragma unroll
                for (int i = 0; i < 4; ++i)
                    xp[bt][i] = fmaf(xrf[m], kk_[m][i], xp[bt][i]);
        }

        // prefetch next x rows (raw barriers keep them in flight)
        int tn = (t + 1 < TSTEPS) ? t + 1 : t;
        float4 xn[NB];
        #pragma unroll
        for (int bt = 0; bt < NB; ++bt)
            xn[bt] = *(const float4*)(xb[bt] + (size_t)tn * DIN + 4 * p);

        #pragma unroll
        for (int s = 0; s < UNFOLDS; ++s) {
            const int pp = s & 1;

            // both batches' h chunks first (independent loads issue together)
            h16x2 hh[NB][4];
            #pragma unroll
            for (int bt = 0; bt < NB; ++bt)
                *(uint4*)&hh[bt][0] = *(const uint4*)&hbuf[pp][bt][8 * p];

            float sv[NB];
            #pragma unroll
            for (int bt = 0; bt < NB; ++bt) {
                float acc[4] = {xp[bt][0], xp[bt][1], xp[bt][2], xp[bt][3]};
                #pragma unroll
                for (int m = 0; m < 4; ++m)
                    #pragma unroll
                    for (int j = 0; j < 4; ++j)
                        acc[j] = dot2(hh[bt][m], w2_[m][j], acc[j]);

                // 16-lane reduce-scatter (R5/R7-verified)
                const bool b0 = (p & 1) != 0;
                const bool b1 = (p & 2) != 0;
                float a0 = b0 ? acc[2] : acc[0];
                float c0 = b0 ? acc[0] : acc[2];
                float r0 = a0 + dpp_f<0xB1>(c0);
                float a1 = b0 ? acc[3] : acc[1];
                float c1 = b0 ? acc[1] : acc[3];
                float r1 = a1 + dpp_f<0xB1>(c1);
                float a2 = b1 ? r1 : r0;
                float c2 = b1 ? r0 : r1;
                float v  = a2 + dpp_f<0x4E>(c2);
                v += dpp_f<0x124>(v);   // row_ror:4
                v += dpp_f<0x128>(v);   // row_ror:8
                sv[bt] = v;
            }

            // gating + semi-implicit Euler, once per lane per batch
            #pragma unroll
            for (int bt = 0; bt < NB; ++bt) {
                float e   = __expf(-sv[bt]);                // f = 1/(1+e)
                float num = fmaf(h_own[bt], e, h_own[bt] + dtA_o);
                float den = fmaf(cden_o, e, cdp_o);
                h_own[bt] = num * __builtin_amdgcn_rcpf(den);
            }

            if (p < 4) {
                hbuf[pp ^ 1][0][u_own] = (_Float16)h_own[0];
                hbuf[pp ^ 1][1][u_own] = (_Float16)h_own[1];
            }

            if (s == UNFOLDS - 1) {
                #pragma unroll
                for (int bt = 0; bt < NB; ++bt) {
                    float q = (p < 4) ? h_own[bt] * ok_o : 0.0f;
                    q += __shfl_xor(q, 1);
                    q += __shfl_xor(q, 2);
                    q += __shfl_xor(q, 4);
                    q += __shfl_xor(q, 8);
                    q += __shfl_xor(q, 16);
                    q += __shfl_xor(q, 32);
                    if (lane == 0) part[bt][wid] = q;
                }
            }

            asm volatile("s_waitcnt lgkmcnt(0)" ::: "memory");
            __builtin_amdgcn_sched_barrier(0);
            __builtin_amdgcn_s_barrier();
            __builtin_amdgcn_sched_barrier(0);
        }

        if (tid == 0) {
            #pragma unroll
            for (int bt = 0; bt < NB; ++bt) {
                float r = ob;
                #pragma unroll
                for (int k = 0; k < 8; ++k) r += part[bt][k];
                out[(size_t)(2 * blockIdx.x + bt) * TSTEPS + t] = r;
            }
        }
        #pragma unroll
        for (int bt = 0; bt < NB; ++bt) xr[bt] = xn[bt];
    }
}

extern "C" void kernel_launch(void* const* d_in, const int* in_sizes, int n_in,
                              void* d_out, int out_size, void* d_ws, size_t ws_size,
                              hipStream_t stream) {
    const float* x     = (const float*)d_in[0];
    const float* kern  = (const float*)d_in[1];
    const float* rk    = (const float*)d_in[2];
    const float* bias  = (const float*)d_in[3];
    const float* tau   = (const float*)d_in[4];
    const float* Avec  = (const float*)d_in[5];
    const float* okern = (const float*)d_in[6];
    const float* obias = (const float*)d_in[7];
    float* out = (float*)d_out;

    ltc_kernel<<<64 / NB, NT, 0, stream>>>(
        x, kern, rk, bias, tau, Avec, okern, obias, out);
}